// Round 4
// baseline (248.003 us; speedup 1.0000x reference)
//
#include <hip/hip_runtime.h>
#include <math.h>

// B,S,D,V,N_BLOCKS = 4096,128,9,5,4
constexpr int Bn = 4096;
constexpr int Sn = 128;
constexpr int Dn = 9;
constexpr int Vn = 5;
constexpr int NBn = 4;

typedef float f2  __attribute__((ext_vector_type(2)));
typedef float f4  __attribute__((ext_vector_type(4)));
typedef short s8v __attribute__((ext_vector_type(8)));   // 8 bf16 (bits)
typedef short s4v __attribute__((ext_vector_type(4)));
typedef unsigned u4v __attribute__((ext_vector_type(4)));

static __device__ __forceinline__ f2 splat(float v) { f2 r; r.x = v; r.y = v; return r; }

// pack two fp32 into a dword of two bf16 (chop rounding)
static __device__ __forceinline__ unsigned pkhi(float a, float b) {
    return (__builtin_bit_cast(unsigned, a) >> 16) |
           (__builtin_bit_cast(unsigned, b) & 0xffff0000u);
}
// residual after bf16-chop
static __device__ __forceinline__ float lof(float a) {
    return a - __builtin_bit_cast(float, __builtin_bit_cast(unsigned, a) & 0xffff0000u);
}

// LDS layout (bytes):
//   Vth [9][132] short : 0     .. 2376   (pad to 2384)  V^T hi, row stride 264B (bank spread)
//   Vtl [9][132] short : 2384  .. 4760   (pad to 4768)
//   KF  [128][32] short: 4768  .. 12960  rows = [Kh(9)+0pad(7) | Kl(9)+0pad(7)], 64B,
//                                        quad i of row r stored at position i^(r&3)
//   QF  [128][32] short: 12960 .. 21152  same for Q (pre-scaled)
//   XB  [128][12] float: 21152 .. 27296  inter-layer activations, row 48B
constexpr int SMEM_BYTES = 27296;

// write one 9-float row as [hi|lo] bf16 slots into KF/QF, quad-XOR swizzled
static __device__ __forceinline__ void write_row_hl(short* rowp, const float v[9], int r) {
    unsigned h[9], l[9];
    #pragma unroll
    for (int e = 0; e < 9; ++e) {
        unsigned u = __builtin_bit_cast(unsigned, v[e]);
        h[e] = u >> 16;
        float hf = __builtin_bit_cast(float, u & 0xffff0000u);
        l[e] = __builtin_bit_cast(unsigned, v[e] - hf) >> 16;
    }
    u4v w0 = (u4v){ h[0] | (h[1] << 16), h[2] | (h[3] << 16),
                    h[4] | (h[5] << 16), h[6] | (h[7] << 16) };
    u4v w1 = (u4v){ h[8], 0u, 0u, 0u };
    u4v w2 = (u4v){ l[0] | (l[1] << 16), l[2] | (l[3] << 16),
                    l[4] | (l[5] << 16), l[6] | (l[7] << 16) };
    u4v w3 = (u4v){ l[8], 0u, 0u, 0u };
    u4v* qp = (u4v*)rowp;
    const int sw = r & 3;
    qp[0 ^ sw] = w0; qp[1 ^ sw] = w1; qp[2 ^ sw] = w2; qp[3 ^ sw] = w3;
}

static __device__ __forceinline__ s8v read_quad(const short* base, int row, int quad) {
    return *(const s8v*)(base + row * 32 + ((quad ^ (row & 3)) * 8));
}

__global__ __launch_bounds__(64) void bert_kernel(
    const int*   __restrict__ tokens,
    const float* __restrict__ emb,
    const float* __restrict__ Wq, const float* __restrict__ bq,
    const float* __restrict__ Wk, const float* __restrict__ bk,
    const float* __restrict__ Wv, const float* __restrict__ bv,
    const float* __restrict__ Wout, const float* __restrict__ bout,
    float*       __restrict__ out)
{
    __shared__ __align__(16) char smem[SMEM_BYTES];
    short* Vth = (short*)smem;                  // [9][132]
    short* Vtl = (short*)(smem + 2384);         // [9][132]
    short* KFb = (short*)(smem + 4768);         // [128][32]
    short* QFb = (short*)(smem + 12960);        // [128][32]
    float* XBf = (float*)(smem + 21152);        // [128][12]

    const int b = blockIdx.x;
    const int t = threadIdx.x;          // 0..63
    const int col = t & 15;             // MFMA n/m lane index
    const int g   = t >> 4;             // MFMA quad
    const float qscale = (1.0f / 3.0f) * 1.44269504f;   // 1/sqrt(D) * log2(e)

    const float inv_freq[Dn] = {
        1.0f, 1.0f,
        0.1291549665f, 0.1291549665f,
        0.0166810054f, 0.0166810054f,
        0.0021544347f, 0.0021544347f,
        0.0002782559f
    };

    // ---- embed + positional encoding: x[d] = {row t, row t+64} ----
    f2 x[Dn];
    {
        const int tok0 = tokens[b * Sn + t];
        const int tok1 = tokens[b * Sn + t + 64];
        #pragma unroll
        for (int d = 0; d < Dn; ++d) {
            const float a0 = (float)t * inv_freq[d];
            const float a1 = (float)(t + 64) * inv_freq[d];
            const float p0 = (d & 1) ? cosf(a0) : sinf(a0);
            const float p1 = (d & 1) ? cosf(a1) : sinf(a1);
            x[d].x = emb[tok0 * Dn + d] + p0;
            x[d].y = emb[tok1 * Dn + d] + p1;
        }
    }

    #pragma unroll 1
    for (int it = 0; it < NBn; ++it) {
        if (it) {
            __syncthreads();   // XB (prev layer output) ready; prev frag reads done
            #pragma unroll
            for (int rr = 0; rr < 2; ++rr) {
                const int r = t + rr * 64;
                const f4* xp = (const f4*)&XBf[r * 12];
                f4 a0 = xp[0], a1 = xp[1], a2 = xp[2];
                float xr[9] = {a0.x, a0.y, a0.z, a0.w, a1.x, a1.y, a1.z, a1.w, a2.x};
                #pragma unroll
                for (int d = 0; d < Dn; ++d) {
                    if (rr) x[d].y = xr[d]; else x[d].x = xr[d];
                }
            }
        }

        const float* wq  = Wq + it * 81;
        const float* wk  = Wk + it * 81;
        const float* wv  = Wv + it * 81;
        const float* bqi = bq + it * 9;
        const float* bki = bk + it * 9;
        const float* bvi = bv + it * 9;

        // ---- phase 1: projections (VALU, packed 2 rows) ----
        f2 q9[9], k9[9], v9[9];
        #pragma unroll
        for (int e = 0; e < Dn; ++e) {
            f2 aq = splat(bqi[e]);
            f2 ak = splat(bki[e]);
            f2 av = splat(bvi[e]);
            #pragma unroll
            for (int d = 0; d < Dn; ++d) {
                aq = __builtin_elementwise_fma(x[d], splat(wq[e * 9 + d]), aq);
                ak = __builtin_elementwise_fma(x[d], splat(wk[e * 9 + d]), ak);
                av = __builtin_elementwise_fma(x[d], splat(wv[e * 9 + d]), av);
            }
            q9[e] = aq * splat(qscale);
            k9[e] = ak;
            v9[e] = av;
        }

        // stage K,Q as [hi|lo] rows; V transposed hi/lo
        #pragma unroll
        for (int rr = 0; rr < 2; ++rr) {
            const int r = t + rr * 64;
            float kv[9], qv[9], vv[9];
            #pragma unroll
            for (int e = 0; e < 9; ++e) {
                kv[e] = rr ? k9[e].y : k9[e].x;
                qv[e] = rr ? q9[e].y : q9[e].x;
                vv[e] = rr ? v9[e].y : v9[e].x;
            }
            write_row_hl(KFb + r * 32, kv, r);
            write_row_hl(QFb + r * 32, qv, r);
            #pragma unroll
            for (int e = 0; e < 9; ++e) {
                unsigned u = __builtin_bit_cast(unsigned, vv[e]);
                Vth[e * 132 + r] = (short)(u >> 16);
                Vtl[e * 132 + r] = (short)(__builtin_bit_cast(unsigned, lof(vv[e])) >> 16);
            }
        }
        __syncthreads();

        // ---- fragments held for the whole layer ----
        s8v kfr[8];
        #pragma unroll
        for (int kt = 0; kt < 8; ++kt)
            kfr[kt] = read_quad(KFb, kt * 16 + col, g);

        // V^T A-frags: step s covers keys [32s..32s+31], slot sigma=g*8+j ->
        // key = (2s + (j>>2))*16 + g*4 + (j&3)
        s8v vh[4], vl[4];
        #pragma unroll
        for (int s = 0; s < 4; ++s) {
            const short* h0 = Vth + col * 132 + 32 * s + 4 * g;
            s4v ha = *(const s4v*)h0;
            s4v hb = *(const s4v*)(h0 + 16);
            vh[s] = __builtin_shufflevector(ha, hb, 0, 1, 2, 3, 4, 5, 6, 7);
            const short* l0 = Vtl + col * 132 + 32 * s + 4 * g;
            s4v la = *(const s4v*)l0;
            s4v lb = *(const s4v*)(l0 + 16);
            vl[s] = __builtin_shufflevector(la, lb, 0, 1, 2, 3, 4, 5, 6, 7);
        }

        // ---- per q-tile: S^T = K.Q^T (2 MFMAs/tile), softmax, O^T = V^T.P^T ----
        #pragma unroll 1
        for (int qt = 0; qt < 8; ++qt) {
            const int q = qt * 16 + col;
            s8v b1 = read_quad(QFb, q, g & 1);        // [Qh|Qh]
            s8v b2 = read_quad(QFb, q, 2 + (g & 1));  // [Ql|Ql]

            f4 acc8[8];
            #pragma unroll
            for (int kt = 0; kt < 8; ++kt) {
                f4 a = __builtin_amdgcn_mfma_f32_16x16x32_bf16(kfr[kt], b1, (f4)(0.0f), 0, 0, 0);
                acc8[kt] = __builtin_amdgcn_mfma_f32_16x16x32_bf16(kfr[kt], b2, a, 0, 0, 0);
            }
            // lane holds S^T[key = kt*16 + g*4 + r][q], log2-scaled
            float mx = acc8[0][0];
            #pragma unroll
            for (int kt = 0; kt < 8; ++kt)
                #pragma unroll
                for (int r = 0; r < 4; ++r)
                    mx = fmaxf(mx, acc8[kt][r]);
            mx = fmaxf(mx, __shfl_xor(mx, 16));
            mx = fmaxf(mx, __shfl_xor(mx, 32));

            float p[32];
            float sm = 0.0f;
            #pragma unroll
            for (int kt = 0; kt < 8; ++kt)
                #pragma unroll
                for (int r = 0; r < 4; ++r) {
                    float e2 = __builtin_amdgcn_exp2f(acc8[kt][r] - mx);
                    p[kt * 4 + r] = e2;
                    sm += e2;
                }
            sm += __shfl_xor(sm, 16);
            sm += __shfl_xor(sm, 32);

            // pack P hi/lo directly into B-frags (register reuse of C layout)
            s8v ph[4], pl[4];
            #pragma unroll
            for (int s = 0; s < 4; ++s) {
                const float* pp = &p[8 * s];
                u4v uh = (u4v){ pkhi(pp[0], pp[1]), pkhi(pp[2], pp[3]),
                                pkhi(pp[4], pp[5]), pkhi(pp[6], pp[7]) };
                ph[s] = __builtin_bit_cast(s8v, uh);
                u4v ul = (u4v){ pkhi(lof(pp[0]), lof(pp[1])), pkhi(lof(pp[2]), lof(pp[3])),
                                pkhi(lof(pp[4]), lof(pp[5])), pkhi(lof(pp[6]), lof(pp[7])) };
                pl[s] = __builtin_bit_cast(s8v, ul);
            }

            f4 oac = (f4)(0.0f);
            #pragma unroll
            for (int s = 0; s < 4; ++s) {
                oac = __builtin_amdgcn_mfma_f32_16x16x32_bf16(vh[s], ph[s], oac, 0, 0, 0);
                oac = __builtin_amdgcn_mfma_f32_16x16x32_bf16(vl[s], ph[s], oac, 0, 0, 0);
                oac = __builtin_amdgcn_mfma_f32_16x16x32_bf16(vh[s], pl[s], oac, 0, 0, 0);
            }
            const float rl = 1.0f / sm;
            oac *= rl;
            // O^T: lane holds col=q, rows d = g*4+{0..3}; rows 12..15 dropped
            if (g < 3)
                *(f4*)&XBf[q * 12 + g * 4] = oac;
        }
        // next layer's top __syncthreads() protects XB/KF/QF/Vt reuse
    }

    __syncthreads();

    // ---- logits + log_softmax from XB ----
    #pragma unroll
    for (int rr = 0; rr < 2; ++rr) {
        const int s = t + rr * 64;
        const f4* xp = (const f4*)&XBf[s * 12];
        f4 a0 = xp[0], a1 = xp[1], a2 = xp[2];
        float xr[9] = {a0.x, a0.y, a0.z, a0.w, a1.x, a1.y, a1.z, a1.w, a2.x};
        float lg[Vn];
        #pragma unroll
        for (int v = 0; v < Vn; ++v) {
            float a = bout[v];
            #pragma unroll
            for (int d = 0; d < Dn; ++d) a += xr[d] * Wout[v * Dn + d];
            lg[v] = a;
        }
        float mm = lg[0];
        #pragma unroll
        for (int v = 1; v < Vn; ++v) mm = fmaxf(mm, lg[v]);
        float sum = 0.0f;
        #pragma unroll
        for (int v = 0; v < Vn; ++v)
            sum += __builtin_amdgcn_exp2f((lg[v] - mm) * 1.44269504f);
        const float lse = __builtin_amdgcn_logf(sum) * 0.69314718f + mm;
        float* op = out + ((size_t)b * Sn + s) * Vn;
        #pragma unroll
        for (int v = 0; v < Vn; ++v) op[v] = lg[v] - lse;
    }
}

extern "C" void kernel_launch(void* const* d_in, const int* in_sizes, int n_in,
                              void* d_out, int out_size, void* d_ws, size_t ws_size,
                              hipStream_t stream) {
    const int*   tokens = (const int*)  d_in[0];
    const float* emb    = (const float*)d_in[1];
    const float* Wq     = (const float*)d_in[2];
    const float* bq_    = (const float*)d_in[3];
    const float* Wk     = (const float*)d_in[4];
    const float* bk_    = (const float*)d_in[5];
    const float* Wv     = (const float*)d_in[6];
    const float* bv_    = (const float*)d_in[7];
    const float* Wout   = (const float*)d_in[8];
    const float* bout_  = (const float*)d_in[9];
    float* out = (float*)d_out;

    bert_kernel<<<dim3(Bn), dim3(64), 0, stream>>>(
        tokens, emb, Wq, bq_, Wk, bk_, Wv, bv_, Wout, bout_, out);
}

// Round 6
// 148.854 us; speedup vs baseline: 1.6661x; 1.6661x over previous
//
#include <hip/hip_runtime.h>
#include <math.h>

// B,S,D,V,N_BLOCKS = 4096,128,9,5,4
constexpr int Bn = 4096;
constexpr int Sn = 128;
constexpr int Dn = 9;
constexpr int Vn = 5;
constexpr int NBn = 4;

typedef float f4 __attribute__((ext_vector_type(4)));
typedef _Float16 h8 __attribute__((ext_vector_type(8)));   // MFMA operand type
typedef __fp16   h2 __attribute__((ext_vector_type(2)));   // cvt_pkrtz result type
typedef unsigned u4v __attribute__((ext_vector_type(4)));
typedef short s4v __attribute__((ext_vector_type(4)));

// LDS layout (bytes). Row stride 80B = 20 banks (odd multiple of 4) so both
// the 4xb128 row writes and the quad frag reads spread uniformly over all
// eight 4-bank groups (8 lanes/group = b128 minimum, zero excess conflict).
//  KF [128] rows x 32 fp16 slots [Kh(9)|z7|Kl(9)|z7], stride 40 shorts (80B)
//  QF same, Q pre-scaled by log2(e)/sqrt(D)
//  VF [16][136] fp16 V^T (rows 9..15 unwritten; reads stay in-region; any
//     NaN from poison only lands in unused D rows 9..15 -> XB cols 9..11)
//  XB [128][12] f32 inter-layer activations, stride 48B
constexpr int KF_OFF = 0;          // 10240
constexpr int QF_OFF = 10240;      // 10240
constexpr int VF_OFF = 20480;      // 16*272 = 4352
constexpr int XB_OFF = 24832;      // 6144
constexpr int SMEM_BYTES = 30976;

// fp16 hi/lo split of a 9-float row into [h|l] MFMA K-slots (4 x b128)
static __device__ __forceinline__ void store_hl_row(short* rowp, const float* v) {
    h2 h01 = __builtin_amdgcn_cvt_pkrtz(v[0], v[1]);
    h2 h23 = __builtin_amdgcn_cvt_pkrtz(v[2], v[3]);
    h2 h45 = __builtin_amdgcn_cvt_pkrtz(v[4], v[5]);
    h2 h67 = __builtin_amdgcn_cvt_pkrtz(v[6], v[7]);
    h2 h8z = __builtin_amdgcn_cvt_pkrtz(v[8], 0.0f);
    h2 l01 = __builtin_amdgcn_cvt_pkrtz(v[0] - (float)h01.x, v[1] - (float)h01.y);
    h2 l23 = __builtin_amdgcn_cvt_pkrtz(v[2] - (float)h23.x, v[3] - (float)h23.y);
    h2 l45 = __builtin_amdgcn_cvt_pkrtz(v[4] - (float)h45.x, v[5] - (float)h45.y);
    h2 l67 = __builtin_amdgcn_cvt_pkrtz(v[6] - (float)h67.x, v[7] - (float)h67.y);
    h2 l8z = __builtin_amdgcn_cvt_pkrtz(v[8] - (float)h8z.x, 0.0f);
    u4v w0 = (u4v){ __builtin_bit_cast(unsigned, h01), __builtin_bit_cast(unsigned, h23),
                    __builtin_bit_cast(unsigned, h45), __builtin_bit_cast(unsigned, h67) };
    u4v w1 = (u4v){ __builtin_bit_cast(unsigned, h8z), 0u, 0u, 0u };
    u4v w2 = (u4v){ __builtin_bit_cast(unsigned, l01), __builtin_bit_cast(unsigned, l23),
                    __builtin_bit_cast(unsigned, l45), __builtin_bit_cast(unsigned, l67) };
    u4v w3 = (u4v){ __builtin_bit_cast(unsigned, l8z), 0u, 0u, 0u };
    u4v* qp = (u4v*)rowp;
    qp[0] = w0; qp[1] = w1; qp[2] = w2; qp[3] = w3;
}

static __device__ __forceinline__ h8 read_quad(const short* base, int row, int quad) {
    return *(const h8*)(base + row * 40 + quad * 8);
}

// One block = one batch, 4 waves cooperating. Threads 0..127 project K + V[0:4),
// threads 128..255 project Q (pre-scaled) + V[4:9). Wave w computes q-tiles
// {2w, 2w+1}: S^T = K.Q^T in fp16 hi/lo (2 MFMAs, exact to 2^-22), softmax in
// exp2 domain, O^T = V^T.P^T single-term fp16 (4 MFMAs, P via v_cvt_pkrtz).
__global__ __launch_bounds__(256, 4) void bert_kernel(
    const int*   __restrict__ tokens,
    const float* __restrict__ emb,
    const float* __restrict__ Wq, const float* __restrict__ bq,
    const float* __restrict__ Wk, const float* __restrict__ bk,
    const float* __restrict__ Wv, const float* __restrict__ bv,
    const float* __restrict__ Wout, const float* __restrict__ bout,
    float*       __restrict__ out)
{
    __shared__ __align__(16) char smem[SMEM_BYTES];
    short* KF = (short*)(smem + KF_OFF);
    short* QF = (short*)(smem + QF_OFF);
    short* VF = (short*)(smem + VF_OFF);
    float* XB = (float*)(smem + XB_OFF);

    const int b   = blockIdx.x;
    const int tid = threadIdx.x;         // 0..255
    const int t   = tid & 63;
    const int w   = tid >> 6;            // wave 0..3
    const int col = t & 15;
    const int g   = t >> 4;
    const bool lowhalf = tid < 128;
    const int r = lowhalf ? tid : tid - 128;    // projection / staging row
    const float qscale = (1.0f / 3.0f) * 1.44269504f;   // 1/sqrt(D) * log2(e)

    // ---- stage 0: embed + positional encoding -> XB ----
    if (lowhalf) {
        const float inv_freq[Dn] = {
            1.0f, 1.0f,
            0.1291549665f, 0.1291549665f,
            0.0166810054f, 0.0166810054f,
            0.0021544347f, 0.0021544347f,
            0.0002782559f
        };
        const int tok = tokens[b * Sn + r];
        float xr[9];
        #pragma unroll
        for (int d = 0; d < Dn; ++d) {
            const float a = (float)r * inv_freq[d];
            const float p = (d & 1) ? cosf(a) : sinf(a);
            xr[d] = emb[tok * Dn + d] + p;
        }
        f4* xp = (f4*)&XB[r * 12];
        xp[0] = (f4){xr[0], xr[1], xr[2], xr[3]};
        xp[1] = (f4){xr[4], xr[5], xr[6], xr[7]};
        xp[2] = (f4){xr[8], 0.0f, 0.0f, 0.0f};
    }
    __syncthreads();

    #pragma unroll 1
    for (int it = 0; it < NBn; ++it) {
        // ---- phase 1: projections + staging ----
        {
            const f4* xp = (const f4*)&XB[r * 12];
            f4 a0 = xp[0], a1 = xp[1], a2 = xp[2];
            float x[9] = {a0.x, a0.y, a0.z, a0.w, a1.x, a1.y, a1.z, a1.w, a2.x};
            const float* wv  = Wv + it * 81;
            const float* bvi = bv + it * 9;
            if (lowhalf) {
                const float* wk  = Wk + it * 81;
                const float* bki = bk + it * 9;
                float kv[9];
                #pragma unroll
                for (int e = 0; e < Dn; ++e) {
                    float ak = bki[e];
                    #pragma unroll
                    for (int d = 0; d < Dn; ++d) ak = fmaf(x[d], wk[e * 9 + d], ak);
                    kv[e] = ak;
                }
                store_hl_row(KF + r * 40, kv);
                #pragma unroll
                for (int e = 0; e < 4; ++e) {
                    float av = bvi[e];
                    #pragma unroll
                    for (int d = 0; d < Dn; ++d) av = fmaf(x[d], wv[e * 9 + d], av);
                    VF[e * 136 + r] = __builtin_bit_cast(short, (_Float16)av);
                }
            } else {
                const float* wq  = Wq + it * 81;
                const float* bqi = bq + it * 9;
                float qv[9];
                #pragma unroll
                for (int e = 0; e < Dn; ++e) {
                    float aq = bqi[e];
                    #pragma unroll
                    for (int d = 0; d < Dn; ++d) aq = fmaf(x[d], wq[e * 9 + d], aq);
                    qv[e] = aq * qscale;
                }
                store_hl_row(QF + r * 40, qv);
                #pragma unroll
                for (int e = 4; e < Dn; ++e) {
                    float av = bvi[e];
                    #pragma unroll
                    for (int d = 0; d < Dn; ++d) av = fmaf(x[d], wv[e * 9 + d], av);
                    VF[e * 136 + r] = __builtin_bit_cast(short, (_Float16)av);
                }
            }
        }
        __syncthreads();

        // ---- phase 2: wave w owns q-tiles 2w, 2w+1 ----
        h8 kfr[8];
        #pragma unroll
        for (int kt = 0; kt < 8; ++kt)
            kfr[kt] = read_quad(KF, kt * 16 + col, g);

        // V^T A-frags with permuted K-dim: slot (g,j) <-> key 16*(2s+(j>>2))+4g+(j&3)
        h8 vf[4];
        #pragma unroll
        for (int s = 0; s < 4; ++s) {
            const short* p0 = VF + col * 136 + 32 * s + 4 * g;
            s4v va = *(const s4v*)p0;
            s4v vb = *(const s4v*)(p0 + 16);
            vf[s] = __builtin_bit_cast(h8,
                __builtin_shufflevector(va, vb, 0, 1, 2, 3, 4, 5, 6, 7));
        }

        #pragma unroll
        for (int ti = 0; ti < 2; ++ti) {
            const int qt = 2 * w + ti;
            const int q  = qt * 16 + col;
            h8 b1 = read_quad(QF, q, g & 1);        // [Qh|Qh]
            h8 b2 = read_quad(QF, q, 2 + (g & 1));  // [Ql|Ql]

            f4 acc[8];
            #pragma unroll
            for (int kt = 0; kt < 8; ++kt) {
                f4 a = __builtin_amdgcn_mfma_f32_16x16x32_f16(kfr[kt], b1, (f4)(0.0f), 0, 0, 0);
                acc[kt] = __builtin_amdgcn_mfma_f32_16x16x32_f16(kfr[kt], b2, a, 0, 0, 0);
            }
            // lane holds S^T[key = kt*16 + 4g + rr][q] (log2 domain)
            f4 m0 = __builtin_elementwise_max(acc[0], acc[1]);
            f4 m1 = __builtin_elementwise_max(acc[2], acc[3]);
            f4 m2 = __builtin_elementwise_max(acc[4], acc[5]);
            f4 m3 = __builtin_elementwise_max(acc[6], acc[7]);
            f4 m4 = __builtin_elementwise_max(__builtin_elementwise_max(m0, m1),
                                              __builtin_elementwise_max(m2, m3));
            float mx = fmaxf(fmaxf(m4.x, m4.y), fmaxf(m4.z, m4.w));
            mx = fmaxf(mx, __shfl_xor(mx, 16));
            mx = fmaxf(mx, __shfl_xor(mx, 32));

            float sm = 0.0f;
            #pragma unroll
            for (int kt = 0; kt < 8; ++kt)
                #pragma unroll
                for (int rr = 0; rr < 4; ++rr) {
                    float e2 = __builtin_amdgcn_exp2f(acc[kt][rr] - mx);
                    acc[kt][rr] = e2;
                    sm += e2;
                }
            sm += __shfl_xor(sm, 16);
            sm += __shfl_xor(sm, 32);

            // P B-frags: slot j=0..3 -> (kt=2s, rr=j); j=4..7 -> (kt=2s+1, rr=j&3)
            f4 oac = (f4)(0.0f);
            #pragma unroll
            for (int s = 0; s < 4; ++s) {
                u4v up = (u4v){
                    __builtin_bit_cast(unsigned, __builtin_amdgcn_cvt_pkrtz(acc[2*s][0],   acc[2*s][1])),
                    __builtin_bit_cast(unsigned, __builtin_amdgcn_cvt_pkrtz(acc[2*s][2],   acc[2*s][3])),
                    __builtin_bit_cast(unsigned, __builtin_amdgcn_cvt_pkrtz(acc[2*s+1][0], acc[2*s+1][1])),
                    __builtin_bit_cast(unsigned, __builtin_amdgcn_cvt_pkrtz(acc[2*s+1][2], acc[2*s+1][3])) };
                oac = __builtin_amdgcn_mfma_f32_16x16x32_f16(vf[s], __builtin_bit_cast(h8, up), oac, 0, 0, 0);
            }
            const float rl = 1.0f / sm;
            oac *= rl;
            // O^T C-layout: lane col = q, rows d = 4g + rr; keep d < 12
            if (g < 3)
                *(f4*)&XB[q * 12 + g * 4] = oac;
        }
        __syncthreads();
    }

    // ---- logits + log_softmax ----
    if (lowhalf) {
        const f4* xp = (const f4*)&XB[r * 12];
        f4 a0 = xp[0], a1 = xp[1], a2 = xp[2];
        float xr[9] = {a0.x, a0.y, a0.z, a0.w, a1.x, a1.y, a1.z, a1.w, a2.x};
        float lg[Vn];
        #pragma unroll
        for (int v = 0; v < Vn; ++v) {
            float a = bout[v];
            #pragma unroll
            for (int d = 0; d < Dn; ++d) a = fmaf(xr[d], Wout[v * Dn + d], a);
            lg[v] = a;
        }
        float mm = lg[0];
        #pragma unroll
        for (int v = 1; v < Vn; ++v) mm = fmaxf(mm, lg[v]);
        float sum = 0.0f;
        #pragma unroll
        for (int v = 0; v < Vn; ++v)
            sum += __builtin_amdgcn_exp2f((lg[v] - mm) * 1.44269504f);
        const float lse = __builtin_amdgcn_logf(sum) * 0.69314718f + mm;
        float* op = out + ((size_t)b * Sn + r) * Vn;
        #pragma unroll
        for (int v = 0; v < Vn; ++v) op[v] = lg[v] - lse;
    }
}

extern "C" void kernel_launch(void* const* d_in, const int* in_sizes, int n_in,
                              void* d_out, int out_size, void* d_ws, size_t ws_size,
                              hipStream_t stream) {
    const int*   tokens = (const int*)  d_in[0];
    const float* emb    = (const float*)d_in[1];
    const float* Wq     = (const float*)d_in[2];
    const float* bq_    = (const float*)d_in[3];
    const float* Wk     = (const float*)d_in[4];
    const float* bk_    = (const float*)d_in[5];
    const float* Wv     = (const float*)d_in[6];
    const float* bv_    = (const float*)d_in[7];
    const float* Wout   = (const float*)d_in[8];
    const float* bout_  = (const float*)d_in[9];
    float* out = (float*)d_out;

    bert_kernel<<<dim3(Bn), dim3(256), 0, stream>>>(
        tokens, emb, Wq, bq_, Wk, bk_, Wv, bv_, Wout, bout_, out);
}